// Round 1
// baseline (124.099 us; speedup 1.0000x reference)
//
#include <hip/hip_runtime.h>

// PointNetKnnInterpolator on MI355X (gfx950).
// R11: attack the per-tile serial chain (latency-bound: MfmaUtil 21 / VALU 36 /
// both pipes idle ~2/3 at 4 waves/SIMD, reg-bound occupancy).
//  - bias-MFMA elimination (60 -> 48 MFMAs/tile, 60 -> 48 frags = 48 KiB):
//      b1a rides Wsa's k=67 slot (raw-h pad is 1.0 and feeds mm3 directly);
//      b0b becomes mm4's accumulator INIT (4 broadcast ds_read_b128 of a
//      64-float LDS vector); b1b is feature-constant so it commutes with the
//      row-max: added post-reduction at the store.
//  - gather double-buffer: next tile's x_idx/pos_y issue at loop top, the
//      dependent x16/pos_x gather issues mid-chain into hn*, consumed next
//      iteration -> the ~1200-cycle dependent-load chain leaves the spine.
//  - mm3+mm1 merged (independent given h / relu(h)) -> 24-MFMA ILP cluster.
// Epilogue (ebuf + xor16/xor32 shuffle-max) kept from R10, verified.

typedef _Float16 f16x8 __attribute__((ext_vector_type(8)));
typedef _Float16 f16x4 __attribute__((ext_vector_type(4)));
typedef float    f32x4 __attribute__((ext_vector_type(4)));

constexpr int NX     = 20000;
constexpr int NROWS  = 50000 * 8;    // NY * K
constexpr int NTILES = NROWS / 16;   // 25000
constexpr int NFRAG  = 48;           // W0a 12 | Wsa 12 | W1a 8 | W0b 8 | W1b 8
constexpr int BW     = 8;            // waves per block
constexpr int BLOCK  = 64 * BW;      // 512
constexpr int TS2    = 72;           // epilogue buffer row stride in f16 (+8 pad)

__global__ void prep_x(const float* __restrict__ x, _Float16* __restrict__ x16) {
    const int i = blockIdx.x * blockDim.x + threadIdx.x;   // one float4 each
    if (i < NX * 16) {
        float4 v = ((const float4*)x)[i];
        f16x4 o = {(_Float16)v.x, (_Float16)v.y, (_Float16)v.z, (_Float16)v.w};
        *(f16x4*)(x16 + (size_t)i * 4) = o;
    }
}

// relu + repack accumulator (C-layout) into the two K=64 B-fragments.
// frag s element j  <->  acc[t=2s+(j>>2)][r=j&3]   (matches PHI weight layout)
static __device__ __forceinline__ void pack_relu(const f32x4* A, f16x8* bf) {
#pragma unroll
    for (int s = 0; s < 2; ++s) {
        f16x8 r;
#pragma unroll
        for (int e = 0; e < 8; ++e) {
            float v = A[2 * s + (e >> 2)][e & 3];
            r[e] = (_Float16)(v > 0.0f ? v : 0.0f);
        }
        bf[s] = r;
    }
}

__global__ __launch_bounds__(BLOCK, 4)
void pointnet_fused(const _Float16* __restrict__ x16,
                    const float* __restrict__ pos_x,
                    const float* __restrict__ pos_y,
                    const int*   __restrict__ x_idx,
                    const float* __restrict__ W0a, const float* __restrict__ b0a,
                    const float* __restrict__ W1a, const float* __restrict__ b1a,
                    const float* __restrict__ Wsa,
                    const float* __restrict__ W0b, const float* __restrict__ b0b,
                    const float* __restrict__ W1b, const float* __restrict__ b1b,
                    float* __restrict__ out)
{
    __shared__ __align__(16) _Float16 bfrag[NFRAG * 64 * 8];   // 48 KiB
    __shared__ __align__(16) _Float16 ebuf[BW][16 * TS2];      // 18 KiB
    __shared__ __align__(16) float    bias3f[64];              // b0b (mm4 acc init)
    __shared__ __align__(16) float    bias5f[64];              // b1b (post-max add)

    const int tid = threadIdx.x;

    // ---- fill weight fragments (A operands, transposed; PHI-permuted K) ----
    // grp0 W0a(identity,+b0a@k67)  grp1 Wsa(identity,+b1a@k67)
    // grp2 W1a(PHI) grp3 W0b(PHI) grp4 W1b(PHI)   -- no bias frags anymore
    for (int p = tid; p < NFRAG * 64; p += BLOCK) {
        const int f = p >> 6, l = p & 63;
        const int q = l >> 4, n0 = l & 15;
        int grp, fl;
        if      (f < 12) { grp = 0; fl = f; }
        else if (f < 24) { grp = 1; fl = f - 12; }
        else if (f < 32) { grp = 2; fl = f - 24; }
        else if (f < 40) { grp = 3; fl = f - 32; }
        else             { grp = 4; fl = f - 40; }
        const int s = fl >> 2, t = fl & 3;
        const int col = t * 16 + n0;
        f16x8 v;
#pragma unroll
        for (int j = 0; j < 8; ++j) {
            const int k = 32 * s + 8 * q + j;
            float val = 0.0f;
            if      (grp == 0) val = (k < 67) ? W0a[k * 64 + col] : (k == 67 ? b0a[col] : 0.0f);
            else if (grp == 1) val = (k < 67) ? Wsa[k * 64 + col] : (k == 67 ? b1a[col] : 0.0f);
            else {
                const float* W = (grp == 2) ? W1a : (grp == 3) ? W0b : W1b;
                const int row = 32 * s + 16 * (j >> 2) + 4 * q + (j & 3);  // PHI(k), s<2
                val = W[row * 64 + col];
            }
            v[j] = (_Float16)val;
        }
        *(f16x8*)&bfrag[p * 8] = v;
    }
    if (tid < 64)       bias3f[tid]      = b0b[tid];
    else if (tid < 128) bias5f[tid - 64] = b1b[tid - 64];
    __syncthreads();

    const int lane = tid & 63;
    const int wv   = tid >> 6;
    const int n0   = lane & 15;   // B col = data row (dr) / A row m = out-feat
    const int q    = lane >> 4;

    _Float16* eb = ebuf[wv];

    // epilogue lane roles
    const int ey  = (lane >> 3) & 1;   // y within tile
    const int efg = lane & 7;          // feature group of 8
    const int esb = lane >> 4;         // sub: covers 2 drs

    const int gwave  = blockIdx.x * BW + wv;
    const int nwaves = gridDim.x * BW;

#define WFRAG(fid) (*(const f16x8*)&bfrag[(((fid) * 64) + lane) * 8])

    // ---- prologue gather for the first tile (all 4096 waves have work) ----
    f16x8 hc0, hc1, hc2;
    {
        const int row = gwave * 16 + n0;
        const int xi  = x_idx[row];
        const _Float16* xp = x16 + (long)xi * 64 + q * 8;
        hc0 = *(const f16x8*)(xp);
        hc1 = *(const f16x8*)(xp + 32);
        f16x8 z = {}; hc2 = z;
        if (q == 0) {
            const int yi = row >> 3;
#pragma unroll
            for (int j = 0; j < 3; ++j)
                hc2[j] = (_Float16)(pos_x[xi * 3 + j] - pos_y[yi * 3 + j]);
            hc2[3] = (_Float16)1.0f;   // k=67 pad: bias hook for b0a/b1a
        }
    }

    for (int tile = gwave; tile < NTILES; tile += nwaves) {
        // ---- issue next tile's index + pos_y loads up front (latency hidden
        //      under this tile's 48-MFMA chain) ----
        const int tnx  = tile + nwaves;
        const int rown = (tnx < NTILES ? tnx : tile) * 16 + n0;  // clamp: in-bounds, unused
        const int xin  = x_idx[rown];
        const int yin  = rown >> 3;
        const float py0 = pos_y[yin * 3 + 0];
        const float py1 = pos_y[yin * 3 + 1];
        const float py2 = pos_y[yin * 3 + 2];

        // relu(h) into separate regs (raw h still needed by mm3)
        f16x8 hr0 = hc0, hr1 = hc1, hr2 = hc2;
#pragma unroll
        for (int j = 0; j < 8; ++j) {
            hr0[j] = hr0[j] > (_Float16)0 ? hr0[j] : (_Float16)0;
            hr1[j] = hr1[j] > (_Float16)0 ? hr1[j] : (_Float16)0;
            hr2[j] = hr2[j] > (_Float16)0 ? hr2[j] : (_Float16)0;
        }

        // ---- merged mm3 (h@Wsa, +b1a via k67) & mm1 (relu(h)@W0a, +b0a via k67):
        //      24 independent MFMAs -> deep ILP at the chain head ----
        f32x4 A1[4], A2[4];
#pragma unroll
        for (int t = 0; t < 4; ++t) {
            A1[t] = (f32x4){0.f, 0.f, 0.f, 0.f};
            A2[t] = (f32x4){0.f, 0.f, 0.f, 0.f};
        }
        {
            const f16x8 hcs[3] = {hc0, hc1, hc2};
            const f16x8 hrs[3] = {hr0, hr1, hr2};
#pragma unroll
            for (int s = 0; s < 3; ++s)
#pragma unroll
                for (int t = 0; t < 4; ++t) {
                    A2[t] = __builtin_amdgcn_mfma_f32_16x16x32_f16(WFRAG(12 + s * 4 + t), hcs[s], A2[t], 0, 0, 0);
                    A1[t] = __builtin_amdgcn_mfma_f32_16x16x32_f16(WFRAG( 0 + s * 4 + t), hrs[s], A1[t], 0, 0, 0);
                }
        }

        // ---- mid-chain: gather NEXT tile's h (consumed next iteration; its
        //      L2 latency hides under mm2..mm5 + epilogue) ----
        f16x8 hn0, hn1, hn2;
        {
            const _Float16* xp = x16 + (long)xin * 64 + q * 8;
            hn0 = *(const f16x8*)(xp);
            hn1 = *(const f16x8*)(xp + 32);
            f16x8 z = {}; hn2 = z;
            if (q == 0) {
                hn2[0] = (_Float16)(pos_x[xin * 3 + 0] - py0);
                hn2[1] = (_Float16)(pos_x[xin * 3 + 1] - py1);
                hn2[2] = (_Float16)(pos_x[xin * 3 + 2] - py2);
                hn2[3] = (_Float16)1.0f;
            }
        }

        // ---- mm2: A2 += (relu(net) @ W1a)^T   (b1a already in A2) ----
        f16x8 bf[2];
        pack_relu(A1, bf);
#pragma unroll
        for (int s = 0; s < 2; ++s)
#pragma unroll
            for (int t = 0; t < 4; ++t)
                A2[t] = __builtin_amdgcn_mfma_f32_16x16x32_f16(WFRAG(24 + s * 4 + t), bf[s], A2[t], 0, 0, 0);

        // ---- mm4: A3 = b0b (broadcast LDS init) + (relu(h2) @ W0b)^T ----
        pack_relu(A2, bf);
        f32x4 A3[4];
#pragma unroll
        for (int t = 0; t < 4; ++t) A3[t] = *(const f32x4*)&bias3f[16 * t + 4 * q];
#pragma unroll
        for (int s = 0; s < 2; ++s)
#pragma unroll
            for (int t = 0; t < 4; ++t)
                A3[t] = __builtin_amdgcn_mfma_f32_16x16x32_f16(WFRAG(32 + s * 4 + t), bf[s], A3[t], 0, 0, 0);

        // ---- mm5: A2 += (relu(net2) @ W1b)^T   (b1b deferred past the max) ----
        pack_relu(A3, bf);
#pragma unroll
        for (int s = 0; s < 2; ++s)
#pragma unroll
            for (int t = 0; t < 4; ++t)
                A2[t] = __builtin_amdgcn_mfma_f32_16x16x32_f16(WFRAG(40 + s * 4 + t), bf[s], A2[t], 0, 0, 0);

        // ---- epilogue: h3^T -> ebuf[dr][feat] (b64 writes, contiguous here) ----
        __threadfence_block();
#pragma unroll
        for (int t = 0; t < 4; ++t) {
            f16x4 w;
#pragma unroll
            for (int r = 0; r < 4; ++r) w[r] = (_Float16)A2[t][r];
            *(f16x4*)&eb[n0 * TS2 + t * 16 + q * 4] = w;   // feat = 16t+4q+r
        }
        __threadfence_block();

        // read 2 drs x 8 feats, max-reduce over 8 drs via xor16/xor32 shuffles
        const int dr0 = ey * 8 + esb * 2;
        f16x8 ra = *(const f16x8*)&eb[dr0 * TS2 + efg * 8];
        f16x8 rb = *(const f16x8*)&eb[(dr0 + 1) * TS2 + efg * 8];
#pragma unroll
        for (int e = 0; e < 8; ++e) ra[e] = ra[e] > rb[e] ? ra[e] : rb[e];
#pragma unroll
        for (int st = 0; st < 2; ++st) {
            union { f16x8 h; int i[4]; } u, v2;
            u.h = ra;
#pragma unroll
            for (int d = 0; d < 4; ++d) v2.i[d] = __shfl_xor(u.i[d], st == 0 ? 16 : 32, 64);
#pragma unroll
            for (int e = 0; e < 8; ++e) ra[e] = ra[e] > v2.h[e] ? ra[e] : v2.h[e];
        }
        if (esb == 0) {
            const f32x4 bb0 = *(const f32x4*)&bias5f[efg * 8];
            const f32x4 bb1 = *(const f32x4*)&bias5f[efg * 8 + 4];
            float4 f0 = {(float)ra[0] + bb0[0], (float)ra[1] + bb0[1],
                         (float)ra[2] + bb0[2], (float)ra[3] + bb0[3]};
            float4 f1 = {(float)ra[4] + bb1[0], (float)ra[5] + bb1[1],
                         (float)ra[6] + bb1[2], (float)ra[7] + bb1[3]};
            float* op = out + (long)(tile * 2 + ey) * 64 + efg * 8;
            *(float4*)op = f0;
            *(float4*)(op + 4) = f1;
        }

        // rotate the gather double-buffer
        hc0 = hn0; hc1 = hn1; hc2 = hn2;
    }
#undef WFRAG
}

extern "C" void kernel_launch(void* const* d_in, const int* in_sizes, int n_in,
                              void* d_out, int out_size, void* d_ws, size_t ws_size,
                              hipStream_t stream) {
    (void)in_sizes; (void)n_in; (void)ws_size; (void)out_size;
    _Float16* x16 = (_Float16*)d_ws;

    prep_x<<<(NX * 16 + 255) / 256, 256, 0, stream>>>((const float*)d_in[0], x16);

    pointnet_fused<<<512, BLOCK, 0, stream>>>(
        x16,
        (const float*)d_in[1],   // pos_x
        (const float*)d_in[2],   // pos_y
        (const int*)  d_in[3],   // x_idx
        (const float*)d_in[5],  (const float*)d_in[6],   // W0a, b0a
        (const float*)d_in[7],  (const float*)d_in[8],   // W1a, b1a
        (const float*)d_in[9],                            // Wsa
        (const float*)d_in[10], (const float*)d_in[11],  // W0b, b0b
        (const float*)d_in[12], (const float*)d_in[13],  // W1b, b1b
        (float*)d_out);
}

// Round 2
// 123.561 us; speedup vs baseline: 1.0044x; 1.0044x over previous
//
#include <hip/hip_runtime.h>

// PointNetKnnInterpolator on MI355X (gfx950).
// R12: 2 tiles per wave iteration. R11 post-mortem: bias-MFMA cut (-20% MFMA,
// -20% LDS frag traffic) bought only 5% -> kernel is bound by the combination
// of (a) weight-fragment LDS re-reads (48 ds_read_b128 = 48KB wave-traffic per
// 16-row tile, ~40-50% of per-CU cycles on the LDS pipe) and (b) the strictly
// serial pack_relu->MFMA stage chain that 4 waves/SIMD can't latency-hide.
// Processing a PAIR of tiles per iteration halves (a) -- every WFRAG read now
// feeds two MFMAs -- and doubles ILP on (b) -- two independent chains
// interleave. Reg budget kept <=128 (16 waves/CU): no prefetch buffer (R11:
// neutral), relu-in-place R10 stage order (mm3 on raw h first), all pair state
// in [2]-arrays with fully-unrolled static indexing.
// Bias scheme (R11, verified): b0a/b1a ride k=67 pad of W0a/Wsa; b0b is mm4's
// accumulator init from LDS; b1b commutes with the row-max, added at store.

typedef _Float16 f16x8 __attribute__((ext_vector_type(8)));
typedef _Float16 f16x4 __attribute__((ext_vector_type(4)));
typedef float    f32x4 __attribute__((ext_vector_type(4)));

constexpr int NX     = 20000;
constexpr int NROWS  = 50000 * 8;    // NY * K
constexpr int NTILES = NROWS / 16;   // 25000
constexpr int NPAIRS = NTILES / 2;   // 12500 (exact)
constexpr int NFRAG  = 48;           // W0a 12 | Wsa 12 | W1a 8 | W0b 8 | W1b 8
constexpr int BW     = 8;            // waves per block
constexpr int BLOCK  = 64 * BW;      // 512
constexpr int TS2    = 72;           // epilogue buffer row stride in f16 (+8 pad)

__global__ void prep_x(const float* __restrict__ x, _Float16* __restrict__ x16) {
    const int i = blockIdx.x * blockDim.x + threadIdx.x;   // one float4 each
    if (i < NX * 16) {
        float4 v = ((const float4*)x)[i];
        f16x4 o = {(_Float16)v.x, (_Float16)v.y, (_Float16)v.z, (_Float16)v.w};
        *(f16x4*)(x16 + (size_t)i * 4) = o;
    }
}

// relu + repack accumulator (C-layout) into the two K=64 B-fragments.
// frag s element j  <->  acc[t=2s+(j>>2)][r=j&3]   (matches PHI weight layout)
static __device__ __forceinline__ void pack_relu(const f32x4* A, f16x8* bf) {
#pragma unroll
    for (int s = 0; s < 2; ++s) {
        f16x8 r;
#pragma unroll
        for (int e = 0; e < 8; ++e) {
            float v = A[2 * s + (e >> 2)][e & 3];
            r[e] = (_Float16)(v > 0.0f ? v : 0.0f);
        }
        bf[s] = r;
    }
}

__global__ __launch_bounds__(BLOCK, 4)
void pointnet_fused(const _Float16* __restrict__ x16,
                    const float* __restrict__ pos_x,
                    const float* __restrict__ pos_y,
                    const int*   __restrict__ x_idx,
                    const float* __restrict__ W0a, const float* __restrict__ b0a,
                    const float* __restrict__ W1a, const float* __restrict__ b1a,
                    const float* __restrict__ Wsa,
                    const float* __restrict__ W0b, const float* __restrict__ b0b,
                    const float* __restrict__ W1b, const float* __restrict__ b1b,
                    float* __restrict__ out)
{
    __shared__ __align__(16) _Float16 bfrag[NFRAG * 64 * 8];   // 48 KiB
    __shared__ __align__(16) _Float16 ebuf[BW][16 * TS2];      // 18 KiB
    __shared__ __align__(16) float    bias3f[64];              // b0b (mm4 acc init)
    __shared__ __align__(16) float    bias5f[64];              // b1b (post-max add)

    const int tid = threadIdx.x;

    // ---- fill weight fragments (A operands, transposed; PHI-permuted K) ----
    // grp0 W0a(identity,+b0a@k67)  grp1 Wsa(identity,+b1a@k67)
    // grp2 W1a(PHI) grp3 W0b(PHI) grp4 W1b(PHI)
    for (int p = tid; p < NFRAG * 64; p += BLOCK) {
        const int f = p >> 6, l = p & 63;
        const int q = l >> 4, n0 = l & 15;
        int grp, fl;
        if      (f < 12) { grp = 0; fl = f; }
        else if (f < 24) { grp = 1; fl = f - 12; }
        else if (f < 32) { grp = 2; fl = f - 24; }
        else if (f < 40) { grp = 3; fl = f - 32; }
        else             { grp = 4; fl = f - 40; }
        const int s = fl >> 2, t = fl & 3;
        const int col = t * 16 + n0;
        f16x8 v;
#pragma unroll
        for (int j = 0; j < 8; ++j) {
            const int k = 32 * s + 8 * q + j;
            float val = 0.0f;
            if      (grp == 0) val = (k < 67) ? W0a[k * 64 + col] : (k == 67 ? b0a[col] : 0.0f);
            else if (grp == 1) val = (k < 67) ? Wsa[k * 64 + col] : (k == 67 ? b1a[col] : 0.0f);
            else {
                const float* W = (grp == 2) ? W1a : (grp == 3) ? W0b : W1b;
                const int row = 32 * s + 16 * (j >> 2) + 4 * q + (j & 3);  // PHI(k), s<2
                val = W[row * 64 + col];
            }
            v[j] = (_Float16)val;
        }
        *(f16x8*)&bfrag[p * 8] = v;
    }
    if (tid < 64)       bias3f[tid]      = b0b[tid];
    else if (tid < 128) bias5f[tid - 64] = b1b[tid - 64];
    __syncthreads();

    const int lane = tid & 63;
    const int wv   = tid >> 6;
    const int n0   = lane & 15;   // B col = data row (dr) / A row m = out-feat
    const int q    = lane >> 4;

    _Float16* eb = ebuf[wv];

    // epilogue lane roles
    const int ey  = (lane >> 3) & 1;   // y within tile
    const int efg = lane & 7;          // feature group of 8
    const int esb = lane >> 4;         // sub: covers 2 drs

    const int gwave  = blockIdx.x * BW + wv;
    const int nwaves = gridDim.x * BW;

#define WFRAG(fid) (*(const f16x8*)&bfrag[(((fid) * 64) + lane) * 8])

    for (int pr = gwave; pr < NPAIRS; pr += nwaves) {
        const int tA = pr * 2;

        // ---- gather both tiles' h (independent -> latencies overlap) ----
        f16x8 h[2][3];
#pragma unroll
        for (int u = 0; u < 2; ++u) {
            const int row = (tA + u) * 16 + n0;
            const int xi  = x_idx[row];
            const _Float16* xp = x16 + (long)xi * 64 + q * 8;
            h[u][0] = *(const f16x8*)(xp);
            h[u][1] = *(const f16x8*)(xp + 32);
            f16x8 z = {};
            h[u][2] = z;
            if (q == 0) {                      // k=64..66 diff, k=67 = 1.0 (bias hook)
                const int yi = row >> 3;
#pragma unroll
                for (int j = 0; j < 3; ++j)
                    h[u][2][j] = (_Float16)(pos_x[xi * 3 + j] - pos_y[yi * 3 + j]);
                h[u][2][3] = (_Float16)1.0f;
            }
        }

        // ---- mm3 on raw h: A2 = (h @ Wsa)^T + b1a (k67 hook) ----
        f32x4 A2[2][4];
#pragma unroll
        for (int u = 0; u < 2; ++u)
#pragma unroll
            for (int t = 0; t < 4; ++t) A2[u][t] = (f32x4){0.f, 0.f, 0.f, 0.f};
#pragma unroll
        for (int s = 0; s < 3; ++s)
#pragma unroll
            for (int t = 0; t < 4; ++t) {
                const f16x8 w = WFRAG(12 + s * 4 + t);     // one LDS read, two MFMAs
                A2[0][t] = __builtin_amdgcn_mfma_f32_16x16x32_f16(w, h[0][s], A2[0][t], 0, 0, 0);
                A2[1][t] = __builtin_amdgcn_mfma_f32_16x16x32_f16(w, h[1][s], A2[1][t], 0, 0, 0);
            }

        // ---- relu h in place (pad 1.0 survives) ----
#pragma unroll
        for (int u = 0; u < 2; ++u)
#pragma unroll
            for (int s = 0; s < 3; ++s)
#pragma unroll
                for (int j = 0; j < 8; ++j) {
                    _Float16 v = h[u][s][j];
                    h[u][s][j] = v > (_Float16)0 ? v : (_Float16)0;
                }

        // ---- mm1: A1 = (relu(h) @ W0a)^T + b0a (k67 hook) ----
        f32x4 A1[2][4];
#pragma unroll
        for (int u = 0; u < 2; ++u)
#pragma unroll
            for (int t = 0; t < 4; ++t) A1[u][t] = (f32x4){0.f, 0.f, 0.f, 0.f};
#pragma unroll
        for (int s = 0; s < 3; ++s)
#pragma unroll
            for (int t = 0; t < 4; ++t) {
                const f16x8 w = WFRAG(s * 4 + t);
                A1[0][t] = __builtin_amdgcn_mfma_f32_16x16x32_f16(w, h[0][s], A1[0][t], 0, 0, 0);
                A1[1][t] = __builtin_amdgcn_mfma_f32_16x16x32_f16(w, h[1][s], A1[1][t], 0, 0, 0);
            }

        // ---- mm2: A2 += (relu(net) @ W1a)^T ----
        f16x8 bf[2][2];
#pragma unroll
        for (int u = 0; u < 2; ++u) pack_relu(A1[u], bf[u]);
#pragma unroll
        for (int s = 0; s < 2; ++s)
#pragma unroll
            for (int t = 0; t < 4; ++t) {
                const f16x8 w = WFRAG(24 + s * 4 + t);
                A2[0][t] = __builtin_amdgcn_mfma_f32_16x16x32_f16(w, bf[0][s], A2[0][t], 0, 0, 0);
                A2[1][t] = __builtin_amdgcn_mfma_f32_16x16x32_f16(w, bf[1][s], A2[1][t], 0, 0, 0);
            }

        // ---- mm4: A3 = b0b (broadcast LDS init) + (relu(h2) @ W0b)^T ----
#pragma unroll
        for (int u = 0; u < 2; ++u) pack_relu(A2[u], bf[u]);
        f32x4 A3[2][4];
#pragma unroll
        for (int u = 0; u < 2; ++u)
#pragma unroll
            for (int t = 0; t < 4; ++t) A3[u][t] = *(const f32x4*)&bias3f[16 * t + 4 * q];
#pragma unroll
        for (int s = 0; s < 2; ++s)
#pragma unroll
            for (int t = 0; t < 4; ++t) {
                const f16x8 w = WFRAG(32 + s * 4 + t);
                A3[0][t] = __builtin_amdgcn_mfma_f32_16x16x32_f16(w, bf[0][s], A3[0][t], 0, 0, 0);
                A3[1][t] = __builtin_amdgcn_mfma_f32_16x16x32_f16(w, bf[1][s], A3[1][t], 0, 0, 0);
            }

        // ---- mm5: A2 += (relu(net2) @ W1b)^T  -> h3^T (b1b deferred past max) ----
#pragma unroll
        for (int u = 0; u < 2; ++u) pack_relu(A3[u], bf[u]);
#pragma unroll
        for (int s = 0; s < 2; ++s)
#pragma unroll
            for (int t = 0; t < 4; ++t) {
                const f16x8 w = WFRAG(40 + s * 4 + t);
                A2[0][t] = __builtin_amdgcn_mfma_f32_16x16x32_f16(w, bf[0][s], A2[0][t], 0, 0, 0);
                A2[1][t] = __builtin_amdgcn_mfma_f32_16x16x32_f16(w, bf[1][s], A2[1][t], 0, 0, 0);
            }

        // ---- epilogue per tile: h3^T -> ebuf -> shuffle-max -> out ----
#pragma unroll
        for (int u = 0; u < 2; ++u) {
            const int tile = tA + u;
            __threadfence_block();
#pragma unroll
            for (int t = 0; t < 4; ++t) {
                f16x4 w;
#pragma unroll
                for (int r = 0; r < 4; ++r) w[r] = (_Float16)A2[u][t][r];
                *(f16x4*)&eb[n0 * TS2 + t * 16 + q * 4] = w;   // feat = 16t+4q+r
            }
            __threadfence_block();

            // read 2 drs x 8 feats, max-reduce over 8 drs via xor16/xor32 shuffles
            const int dr0 = ey * 8 + esb * 2;
            f16x8 ra = *(const f16x8*)&eb[dr0 * TS2 + efg * 8];
            f16x8 rb = *(const f16x8*)&eb[(dr0 + 1) * TS2 + efg * 8];
#pragma unroll
            for (int e = 0; e < 8; ++e) ra[e] = ra[e] > rb[e] ? ra[e] : rb[e];
#pragma unroll
            for (int st = 0; st < 2; ++st) {
                union { f16x8 h; int i[4]; } uu, v2;
                uu.h = ra;
#pragma unroll
                for (int d = 0; d < 4; ++d) v2.i[d] = __shfl_xor(uu.i[d], st == 0 ? 16 : 32, 64);
#pragma unroll
                for (int e = 0; e < 8; ++e) ra[e] = ra[e] > v2.h[e] ? ra[e] : v2.h[e];
            }
            if (esb == 0) {
                const f32x4 bb0 = *(const f32x4*)&bias5f[efg * 8];
                const f32x4 bb1 = *(const f32x4*)&bias5f[efg * 8 + 4];
                float4 f0 = {(float)ra[0] + bb0[0], (float)ra[1] + bb0[1],
                             (float)ra[2] + bb0[2], (float)ra[3] + bb0[3]};
                float4 f1 = {(float)ra[4] + bb1[0], (float)ra[5] + bb1[1],
                             (float)ra[6] + bb1[2], (float)ra[7] + bb1[3]};
                float* op = out + (long)(tile * 2 + ey) * 64 + efg * 8;
                *(float4*)op = f0;
                *(float4*)(op + 4) = f1;
            }
        }
    }
#undef WFRAG
}

extern "C" void kernel_launch(void* const* d_in, const int* in_sizes, int n_in,
                              void* d_out, int out_size, void* d_ws, size_t ws_size,
                              hipStream_t stream) {
    (void)in_sizes; (void)n_in; (void)ws_size; (void)out_size;
    _Float16* x16 = (_Float16*)d_ws;

    prep_x<<<(NX * 16 + 255) / 256, 256, 0, stream>>>((const float*)d_in[0], x16);

    pointnet_fused<<<512, BLOCK, 0, stream>>>(
        x16,
        (const float*)d_in[1],   // pos_x
        (const float*)d_in[2],   // pos_y
        (const int*)  d_in[3],   // x_idx
        (const float*)d_in[5],  (const float*)d_in[6],   // W0a, b0a
        (const float*)d_in[7],  (const float*)d_in[8],   // W1a, b1a
        (const float*)d_in[9],                            // Wsa
        (const float*)d_in[10], (const float*)d_in[11],  // W0b, b0b
        (const float*)d_in[12], (const float*)d_in[13],  // W1b, b1b
        (float*)d_out);
}